// Round 3
// baseline (63.002 us; speedup 1.0000x reference)
//
#include <hip/hip_runtime.h>
#include <math.h>

// ---------------------------------------------------------------------------
// SpikingColorVision: 4 pops x 8 ch Izhikevich RS neurons, 1000 Euler steps.
// Latency-bound single-wave serial recurrence, measured ~6.6ns/dependent-op
// (=> effective clock ~750MHz). This round:
//  (a) loop-carried chain cut 6 -> 4 ops by prefolding TWO current planes:
//      i2 = Ib + 0.3*eps + 110  (spike test:  Q = 0.04v^2+6v+i2 >= u)
//      i3 = Ib + 0.3*eps + 140  (integrate:  vn = 0.04v^2+6v+i3 - u)
//  (b) clock-ramp burner folded into the prep kernel (2016 blocks of dummy
//      FMA) to test the DVFS hypothesis; sim dispatch time in rocprof
//      separates the two effects.
// ---------------------------------------------------------------------------

// Fast step. Chain: v -> w -> vq -> vn -> sel (4); u -> cmp -> sel (2);
// u -> un -> u8 -> sel (3). ~12.5 VALU/step.
#define FSTEP2(i2v, i3v) do {                            \
    float w_  = __builtin_fmaf(0.04f, v, 6.0f);          \
    float Q_  = __builtin_fmaf(w_, v, (i2v));            \
    float vq_ = __builtin_fmaf(w_, v, (i3v));            \
    bool  sp_ = (Q_ >= u);                               \
    float vn_ = vq_ - u;                                 \
    float z_  = 0.004f * v;                              \
    v = sp_ ? -65.0f : vn_;                              \
    float un_ = __builtin_fmaf(0.98f, u, z_);            \
    float u8_ = un_ + 8.0f;                              \
    u = sp_ ? u8_ : un_;                                 \
    float g_  = sp_ ? 0.05f : 0.0f;                      \
    rate = __builtin_fmaf(0.95f, rate, g_);              \
  } while (0)

// Exact step (fallback path only) — mirrors reference op-for-op.
#define STEP_EXACT(eps) do {                             \
    float I_ = Ib + (eps) * 0.3f;                        \
    float q_ = 0.04f * v;                                \
    q_ = q_ * v;                                         \
    q_ = q_ + 5.0f * v;                                  \
    q_ = q_ + 140.0f;                                    \
    q_ = q_ - u;                                         \
    q_ = q_ + I_;                                        \
    float vn_ = v + q_;                                  \
    float un_ = u + 0.02f * (0.2f * v - u);              \
    bool  sp_ = (vn_ >= 30.0f);                          \
    float s_  = sp_ ? 1.0f : 0.0f;                       \
    v = sp_ ? -65.0f : vn_;                              \
    u = un_ + s_ * 8.0f;                                 \
    rate = 0.95f * rate + 0.05f * s_;                    \
  } while (0)

// Channel means + opponency outputs; lane holds rate for neuron lane&31.
__device__ __forceinline__ void write_outputs(float rate, int lane,
                                              float* __restrict__ out) {
#pragma clang fp contract(off)
  float rsum = rate;
  rsum += __shfl_xor(rsum, 1);
  rsum += __shfl_xor(rsum, 2);
  rsum += __shfl_xor(rsum, 4);
  float mean = rsum / 8.0f;            // exact /8
  float m_uv = __shfl(mean, 0);
  float m_bl = __shfl(mean, 8);
  float m_gr = __shfl(mean, 16);
  float m_rd = __shfl(mean, 24);
  if (lane == 0) {
    out[0] = m_uv;
    out[1] = m_bl;
    out[2] = m_gr;
    out[3] = m_rd;
    out[4] = m_rd - m_gr;
    out[5] = (m_uv + m_bl) / 2.0f - (m_gr + m_rd) / 2.0f;
  }
}

// Drives from the 800 retinal type values (exact integer counts -> any
// reduction order is exact). Every thread of the block gets all 4 Ib values.
__device__ void block_drives(const float* __restrict__ retL,
                             const float* __restrict__ retR,
                             float Ib[4]) {
#pragma clang fp contract(off)
  __shared__ float red[4][8];
  const int tid = threadIdx.x;
  float f = 0.0f, e = 0.0f, r = 0.0f, cp = 0.0f;
  for (int i = tid; i < 800; i += blockDim.x) {
    float t = (i < 400) ? retL[i] : retR[i - 400];
    f  += (t > 0.7f) ? 1.0f : 0.0f;
    e  += (fabsf(t - 0.5f)  < 0.1f) ? 1.0f : 0.0f;
    r  += (fabsf(t - 0.75f) < 0.1f) ? 1.0f : 0.0f;
    cp += (fabsf(t - 0.25f) < 0.1f) ? 1.0f : 0.0f;
  }
#pragma unroll
  for (int off = 1; off < 64; off <<= 1) {
    f  += __shfl_xor(f,  off);
    e  += __shfl_xor(e,  off);
    r  += __shfl_xor(r,  off);
    cp += __shfl_xor(cp, off);
  }
  const int nw = blockDim.x >> 6;
  if ((tid & 63) == 0) {
    int w = tid >> 6;
    red[0][w] = f; red[1][w] = e; red[2][w] = r; red[3][w] = cp;
  }
  __syncthreads();
  f = 0.0f; e = 0.0f; r = 0.0f; cp = 0.0f;
  for (int w = 0; w < nw; ++w) {
    f += red[0][w]; e += red[1][w]; r += red[2][w]; cp += red[3][w];
  }
  float total = f + e + r + cp + 1e-8f;
  Ib[0] = ((f * 0.1f + e * 0.05f + cp * 0.8f + r * 0.2f) / total) * 10.0f + (-2.0f);
  Ib[1] = ((f * 0.2f + e * 0.1f  + cp * 0.5f + r * 0.3f) / total) * 10.0f + (-2.0f);
  Ib[2] = ((f * 0.8f + e * 0.3f  + cp * 0.3f + r * 0.3f) / total) * 10.0f + (-2.0f);
  Ib[3] = ((f * 0.4f + e * 0.7f  + cp * 0.2f + r * 0.3f) / total) * 10.0f + (-2.0f);
}

// Prep: blocks [0,32) compute drives + write the two prefolded current
// planes (layout [plane][32][S+16], 16-float zero pad). Blocks [32, grid)
// are a deterministic FMA burner to pull SCLK up (DVFS probe).
#define PREP_BLOCKS 32
__global__ void scv_prep_kernel(const float* __restrict__ retL,
                                const float* __restrict__ retR,
                                const float* __restrict__ noise,
                                float* __restrict__ noiseT, int S,
                                int burn_iters) {
#pragma clang fp contract(off)
  if (blockIdx.x >= PREP_BLOCKS) {
    float x = (float)threadIdx.x;
    for (int i = 0; i < burn_iters; ++i)
      x = __builtin_fmaf(x, 0.9999999f, 1e-7f);
    asm volatile("" :: "v"(x));   // keep live, no DCE
    return;
  }

  float Ib[4];
  block_drives(retL, retR, Ib);

  int stride = S + 16;
  int plane = 32 * stride;
  for (int o = blockIdx.x * blockDim.x + threadIdx.x; o < plane;
       o += PREP_BLOCKS * blockDim.x) {
    int n = o / stride;
    int t = o - n * stride;
    float val = (t < S) ? (Ib[n >> 3] + noise[t * 32 + n] * 0.3f) : 0.0f;
    noiseT[o]         = (t < S) ? (val + 110.0f) : 0.0f;
    noiseT[o + plane] = (t < S) ? (val + 140.0f) : 0.0f;
  }
}

// Main simulation: one block, one 64-lane wave. neuron = lane & 31.
__global__ __launch_bounds__(64) void scv_sim_kernel(
    const float* __restrict__ noiseT, float* __restrict__ out, int S) {
  const int lane = threadIdx.x;
  const int neuron = lane & 31;
  const int stride4 = (S + 16) >> 2;
  const float4* s2 =
      reinterpret_cast<const float4*>(noiseT) + (size_t)neuron * stride4;
  const float4* s3 = s2 + (size_t)32 * stride4;

  float v = -65.0f;
  float u = -13.0f;   // 0.2f * -65.0f exactly
  float rate = 0.0f;

  int nChunks = S >> 2;          // 4 steps per float4
  float4 a0 = s2[0], a1 = s2[1], a2 = s2[2], a3 = s2[3];
  float4 c0 = s3[0], c1 = s3[1], c2 = s3[2], c3 = s3[3];
  int cG = nChunks & ~3;
  for (int c = 0; c < cG; c += 4) {
    // issue next-iteration loads first (16-step prefetch distance)
    float4 na0 = s2[c + 4], na1 = s2[c + 5], na2 = s2[c + 6], na3 = s2[c + 7];
    float4 nc0 = s3[c + 4], nc1 = s3[c + 5], nc2 = s3[c + 6], nc3 = s3[c + 7];
    FSTEP2(a0.x, c0.x); FSTEP2(a0.y, c0.y); FSTEP2(a0.z, c0.z); FSTEP2(a0.w, c0.w);
    FSTEP2(a1.x, c1.x); FSTEP2(a1.y, c1.y); FSTEP2(a1.z, c1.z); FSTEP2(a1.w, c1.w);
    FSTEP2(a2.x, c2.x); FSTEP2(a2.y, c2.y); FSTEP2(a2.z, c2.z); FSTEP2(a2.w, c2.w);
    FSTEP2(a3.x, c3.x); FSTEP2(a3.y, c3.y); FSTEP2(a3.z, c3.z); FSTEP2(a3.w, c3.w);
    a0 = na0; a1 = na1; a2 = na2; a3 = na3;
    c0 = nc0; c1 = nc1; c2 = nc2; c3 = nc3;
  }
  int rem = nChunks - cG;
  if (rem >= 1) { FSTEP2(a0.x, c0.x); FSTEP2(a0.y, c0.y); FSTEP2(a0.z, c0.z); FSTEP2(a0.w, c0.w); }
  if (rem >= 2) { FSTEP2(a1.x, c1.x); FSTEP2(a1.y, c1.y); FSTEP2(a1.z, c1.z); FSTEP2(a1.w, c1.w); }
  if (rem >= 3) { FSTEP2(a2.x, c2.x); FSTEP2(a2.y, c2.y); FSTEP2(a2.z, c2.z); FSTEP2(a2.w, c2.w); }

  write_outputs(rate, lane, out);
}

// Fallback for odd S / tiny workspace: exact reference math, raw noise layout.
__global__ __launch_bounds__(64) void scv_sim_fallback(
    const float* __restrict__ retL, const float* __restrict__ retR,
    const float* __restrict__ noise, float* __restrict__ out, int S) {
#pragma clang fp contract(off)
  const int lane = threadIdx.x;
  float f = 0.0f, e = 0.0f, r = 0.0f, cp = 0.0f;
  for (int i = lane; i < 800; i += 64) {
    float t = (i < 400) ? retL[i] : retR[i - 400];
    f  += (t > 0.7f) ? 1.0f : 0.0f;
    e  += (fabsf(t - 0.5f)  < 0.1f) ? 1.0f : 0.0f;
    r  += (fabsf(t - 0.75f) < 0.1f) ? 1.0f : 0.0f;
    cp += (fabsf(t - 0.25f) < 0.1f) ? 1.0f : 0.0f;
  }
#pragma unroll
  for (int off = 1; off < 64; off <<= 1) {
    f  += __shfl_xor(f,  off);
    e  += __shfl_xor(e,  off);
    r  += __shfl_xor(r,  off);
    cp += __shfl_xor(cp, off);
  }
  float total = f + e + r + cp + 1e-8f;
  int p = (lane >> 3) & 3;
  float dv;
  if (p == 0)      dv = (f * 0.1f + e * 0.05f + cp * 0.8f + r * 0.2f) / total;
  else if (p == 1) dv = (f * 0.2f + e * 0.1f  + cp * 0.5f + r * 0.3f) / total;
  else if (p == 2) dv = (f * 0.8f + e * 0.3f  + cp * 0.3f + r * 0.3f) / total;
  else             dv = (f * 0.4f + e * 0.7f  + cp * 0.2f + r * 0.3f) / total;
  float Ib = dv * 10.0f + (-2.0f);

  float v = -65.0f;
  float u = -13.0f;
  float rate = 0.0f;

  const int neuron = lane & 31;
  float nxt = (S > 0) ? noise[neuron] : 0.0f;
  for (int t = 0; t < S; ++t) {
    float cur = nxt;
    nxt = (t + 1 < S) ? noise[(t + 1) * 32 + neuron] : 0.0f;
    STEP_EXACT(cur);
  }

  write_outputs(rate, lane, out);
}

extern "C" void kernel_launch(void* const* d_in, const int* in_sizes, int n_in,
                              void* d_out, int out_size, void* d_ws,
                              size_t ws_size, hipStream_t stream) {
  const float* retL  = (const float*)d_in[0];
  const float* retR  = (const float*)d_in[1];
  const float* noise = (const float*)d_in[2];
  float* out = (float*)d_out;
  (void)n_in; (void)out_size;

  const int S = in_sizes[2] / 32;  // substeps
  const size_t needed = (size_t)2 * (S + 16) * 32 * sizeof(float);

  if (ws_size >= needed && (S % 4) == 0 && S >= 16) {
    float* noiseT = (float*)d_ws;
    // 2048 blocks: 32 prep + 2016 burner (DVFS clock-ramp probe).
    hipLaunchKernelGGL(scv_prep_kernel, dim3(2048), dim3(256), 0, stream,
                       retL, retR, noise, noiseT, S, 768);
    hipLaunchKernelGGL(scv_sim_kernel, dim3(1), dim3(64), 0, stream, noiseT,
                       out, S);
  } else {
    hipLaunchKernelGGL(scv_sim_fallback, dim3(1), dim3(64), 0, stream, retL,
                       retR, noise, out, S);
  }
}

// Round 4
// 35.032 us; speedup vs baseline: 1.7984x; 1.7984x over previous
//
#include <hip/hip_runtime.h>
#include <math.h>

// ---------------------------------------------------------------------------
// SpikingColorVision: 4 pops x 8 ch Izhikevich RS neurons, 1000 Euler steps.
// Latency-bound single-wave serial recurrence (~6.6ns per dependent VALU op
// on this part at lone-wave clocks). R4:
//  - burner removed (R3 showed DVFS cannot ramp within a graph replay; it
//    only added ~20us of serialized prep time)
//  - ONE prefolded current plane: i3[n][t] = Ib[pop(n)] + 0.3*eps + 140
//  - spike test on vn directly (vn >= 30), d3 = i3 - u computed off-chain:
//      d3 = fma(-0.004, U, i3)   (U = 250*u scaled state)
//      w  = fma(0.04, v, 6)
//      vn = fma(w, v, d3)        chain: v->w->vn->cmp->sel = 4 hops
//      Un = fma(0.98, U, v)      (u-recurrence in scaled space, no 0.004v op)
//  - 10 VALU/step total (was ~13)
// ---------------------------------------------------------------------------

// Fast step. i3v = precomputed Ib + 0.3*eps + 140. U = 250*u.
#define FSTEP3(i3v) do {                                 \
    float d3_ = __builtin_fmaf(-0.004f, U, (i3v));       \
    float w_  = __builtin_fmaf(0.04f, v, 6.0f);          \
    float Un_ = __builtin_fmaf(0.98f, U, v);             \
    float vn_ = __builtin_fmaf(w_, v, d3_);              \
    bool  sp_ = (vn_ >= 30.0f);                          \
    v = sp_ ? -65.0f : vn_;                              \
    float U8_ = Un_ + 2000.0f;                           \
    U = sp_ ? U8_ : Un_;                                 \
    float g_  = sp_ ? 0.05f : 0.0f;                      \
    rate = __builtin_fmaf(0.95f, rate, g_);              \
  } while (0)

// Exact step (fallback path only) — mirrors reference op-for-op.
#define STEP_EXACT(eps) do {                             \
    float I_ = Ib + (eps) * 0.3f;                        \
    float q_ = 0.04f * v;                                \
    q_ = q_ * v;                                         \
    q_ = q_ + 5.0f * v;                                  \
    q_ = q_ + 140.0f;                                    \
    q_ = q_ - u;                                         \
    q_ = q_ + I_;                                        \
    float vn_ = v + q_;                                  \
    float un_ = u + 0.02f * (0.2f * v - u);              \
    bool  sp_ = (vn_ >= 30.0f);                          \
    float s_  = sp_ ? 1.0f : 0.0f;                       \
    v = sp_ ? -65.0f : vn_;                              \
    u = un_ + s_ * 8.0f;                                 \
    rate = 0.95f * rate + 0.05f * s_;                    \
  } while (0)

// Channel means + opponency outputs; lane holds rate for neuron lane&31.
__device__ __forceinline__ void write_outputs(float rate, int lane,
                                              float* __restrict__ out) {
#pragma clang fp contract(off)
  float rsum = rate;
  rsum += __shfl_xor(rsum, 1);
  rsum += __shfl_xor(rsum, 2);
  rsum += __shfl_xor(rsum, 4);
  float mean = rsum / 8.0f;            // exact /8
  float m_uv = __shfl(mean, 0);
  float m_bl = __shfl(mean, 8);
  float m_gr = __shfl(mean, 16);
  float m_rd = __shfl(mean, 24);
  if (lane == 0) {
    out[0] = m_uv;
    out[1] = m_bl;
    out[2] = m_gr;
    out[3] = m_rd;
    out[4] = m_rd - m_gr;
    out[5] = (m_uv + m_bl) / 2.0f - (m_gr + m_rd) / 2.0f;
  }
}

// Drives from the 800 retinal type values (exact integer counts -> any
// reduction order is exact). Every thread of the block gets all 4 Ib values.
__device__ void block_drives(const float* __restrict__ retL,
                             const float* __restrict__ retR,
                             float Ib[4]) {
#pragma clang fp contract(off)
  __shared__ float red[4][8];
  const int tid = threadIdx.x;
  float f = 0.0f, e = 0.0f, r = 0.0f, cp = 0.0f;
  for (int i = tid; i < 800; i += blockDim.x) {
    float t = (i < 400) ? retL[i] : retR[i - 400];
    f  += (t > 0.7f) ? 1.0f : 0.0f;
    e  += (fabsf(t - 0.5f)  < 0.1f) ? 1.0f : 0.0f;
    r  += (fabsf(t - 0.75f) < 0.1f) ? 1.0f : 0.0f;
    cp += (fabsf(t - 0.25f) < 0.1f) ? 1.0f : 0.0f;
  }
#pragma unroll
  for (int off = 1; off < 64; off <<= 1) {
    f  += __shfl_xor(f,  off);
    e  += __shfl_xor(e,  off);
    r  += __shfl_xor(r,  off);
    cp += __shfl_xor(cp, off);
  }
  const int nw = blockDim.x >> 6;
  if ((tid & 63) == 0) {
    int w = tid >> 6;
    red[0][w] = f; red[1][w] = e; red[2][w] = r; red[3][w] = cp;
  }
  __syncthreads();
  f = 0.0f; e = 0.0f; r = 0.0f; cp = 0.0f;
  for (int w = 0; w < nw; ++w) {
    f += red[0][w]; e += red[1][w]; r += red[2][w]; cp += red[3][w];
  }
  float total = f + e + r + cp + 1e-8f;
  Ib[0] = ((f * 0.1f + e * 0.05f + cp * 0.8f + r * 0.2f) / total) * 10.0f + (-2.0f);
  Ib[1] = ((f * 0.2f + e * 0.1f  + cp * 0.5f + r * 0.3f) / total) * 10.0f + (-2.0f);
  Ib[2] = ((f * 0.8f + e * 0.3f  + cp * 0.3f + r * 0.3f) / total) * 10.0f + (-2.0f);
  Ib[3] = ((f * 0.4f + e * 0.7f  + cp * 0.2f + r * 0.3f) / total) * 10.0f + (-2.0f);
}

// Prep: drives + transpose-with-fold, one plane:
// i3[n][t] = Ib[pop(n)] + noise[t][n]*0.3 + 140, layout [32][S+16]
// (16-float zero pad so sim prefetch never reads OOB).
__global__ void scv_prep_kernel(const float* __restrict__ retL,
                                const float* __restrict__ retR,
                                const float* __restrict__ noise,
                                float* __restrict__ noiseT, int S) {
#pragma clang fp contract(off)
  float Ib[4];
  block_drives(retL, retR, Ib);

  int stride = S + 16;
  int total = 32 * stride;
  for (int o = blockIdx.x * blockDim.x + threadIdx.x; o < total;
       o += gridDim.x * blockDim.x) {
    int n = o / stride;
    int t = o - n * stride;
    float val = (Ib[n >> 3] + noise[t * 32 + n] * 0.3f) + 140.0f;
    noiseT[o] = (t < S) ? val : 0.0f;
  }
}

// Main simulation: one block, one 64-lane wave. neuron = lane & 31
// (upper 32 lanes duplicate; wave64 issue cost is identical either way).
__global__ __launch_bounds__(64) void scv_sim_kernel(
    const float* __restrict__ noiseT, float* __restrict__ out, int S) {
  const int lane = threadIdx.x;
  const int neuron = lane & 31;
  const int stride4 = (S + 16) >> 2;
  const float4* src =
      reinterpret_cast<const float4*>(noiseT) + (size_t)neuron * stride4;

  float v = -65.0f;
  float U = -3250.0f;   // 250 * u0, u0 = -13 exactly
  float rate = 0.0f;

  int nChunks = S >> 2;          // 4 steps per float4
  float4 b0 = src[0], b1 = src[1], b2 = src[2], b3 = src[3];
  int cG = nChunks & ~3;
  for (int c = 0; c < cG; c += 4) {
    // issue next-iteration loads first (16-step prefetch distance)
    float4 n0 = src[c + 4], n1 = src[c + 5], n2 = src[c + 6], n3 = src[c + 7];
    FSTEP3(b0.x); FSTEP3(b0.y); FSTEP3(b0.z); FSTEP3(b0.w);
    FSTEP3(b1.x); FSTEP3(b1.y); FSTEP3(b1.z); FSTEP3(b1.w);
    FSTEP3(b2.x); FSTEP3(b2.y); FSTEP3(b2.z); FSTEP3(b2.w);
    FSTEP3(b3.x); FSTEP3(b3.y); FSTEP3(b3.z); FSTEP3(b3.w);
    b0 = n0; b1 = n1; b2 = n2; b3 = n3;
  }
  int rem = nChunks - cG;
  if (rem >= 1) { FSTEP3(b0.x); FSTEP3(b0.y); FSTEP3(b0.z); FSTEP3(b0.w); }
  if (rem >= 2) { FSTEP3(b1.x); FSTEP3(b1.y); FSTEP3(b1.z); FSTEP3(b1.w); }
  if (rem >= 3) { FSTEP3(b2.x); FSTEP3(b2.y); FSTEP3(b2.z); FSTEP3(b2.w); }

  write_outputs(rate, lane, out);
}

// Fallback for odd S / tiny workspace: exact reference math, raw noise layout.
__global__ __launch_bounds__(64) void scv_sim_fallback(
    const float* __restrict__ retL, const float* __restrict__ retR,
    const float* __restrict__ noise, float* __restrict__ out, int S) {
#pragma clang fp contract(off)
  const int lane = threadIdx.x;
  float f = 0.0f, e = 0.0f, r = 0.0f, cp = 0.0f;
  for (int i = lane; i < 800; i += 64) {
    float t = (i < 400) ? retL[i] : retR[i - 400];
    f  += (t > 0.7f) ? 1.0f : 0.0f;
    e  += (fabsf(t - 0.5f)  < 0.1f) ? 1.0f : 0.0f;
    r  += (fabsf(t - 0.75f) < 0.1f) ? 1.0f : 0.0f;
    cp += (fabsf(t - 0.25f) < 0.1f) ? 1.0f : 0.0f;
  }
#pragma unroll
  for (int off = 1; off < 64; off <<= 1) {
    f  += __shfl_xor(f,  off);
    e  += __shfl_xor(e,  off);
    r  += __shfl_xor(r,  off);
    cp += __shfl_xor(cp, off);
  }
  float total = f + e + r + cp + 1e-8f;
  int p = (lane >> 3) & 3;
  float dv;
  if (p == 0)      dv = (f * 0.1f + e * 0.05f + cp * 0.8f + r * 0.2f) / total;
  else if (p == 1) dv = (f * 0.2f + e * 0.1f  + cp * 0.5f + r * 0.3f) / total;
  else if (p == 2) dv = (f * 0.8f + e * 0.3f  + cp * 0.3f + r * 0.3f) / total;
  else             dv = (f * 0.4f + e * 0.7f  + cp * 0.2f + r * 0.3f) / total;
  float Ib = dv * 10.0f + (-2.0f);

  float v = -65.0f;
  float u = -13.0f;
  float rate = 0.0f;

  const int neuron = lane & 31;
  float nxt = (S > 0) ? noise[neuron] : 0.0f;
  for (int t = 0; t < S; ++t) {
    float cur = nxt;
    nxt = (t + 1 < S) ? noise[(t + 1) * 32 + neuron] : 0.0f;
    STEP_EXACT(cur);
  }

  write_outputs(rate, lane, out);
}

extern "C" void kernel_launch(void* const* d_in, const int* in_sizes, int n_in,
                              void* d_out, int out_size, void* d_ws,
                              size_t ws_size, hipStream_t stream) {
  const float* retL  = (const float*)d_in[0];
  const float* retR  = (const float*)d_in[1];
  const float* noise = (const float*)d_in[2];
  float* out = (float*)d_out;
  (void)n_in; (void)out_size;

  const int S = in_sizes[2] / 32;  // substeps
  const size_t needed = (size_t)(S + 16) * 32 * sizeof(float);

  if (ws_size >= needed && (S % 4) == 0 && S >= 16) {
    float* noiseT = (float*)d_ws;
    hipLaunchKernelGGL(scv_prep_kernel, dim3(32), dim3(256), 0, stream,
                       retL, retR, noise, noiseT, S);
    hipLaunchKernelGGL(scv_sim_kernel, dim3(1), dim3(64), 0, stream, noiseT,
                       out, S);
  } else {
    hipLaunchKernelGGL(scv_sim_fallback, dim3(1), dim3(64), 0, stream, retL,
                       retR, noise, out, S);
  }
}